// Round 8
// baseline (327.833 us; speedup 1.0000x reference)
//
#include <hip/hip_runtime.h>
#include <hip/hip_fp16.h>

// Problem constants (from reference)
constexpr int BATCH    = 4096;
constexpr int IN_DIM   = 1024;
constexpr int HIDDEN   = 8192;
constexpr int N_LAYERS = 6;
constexpr int N_STAGES = N_LAYERS / 2;   // 3 fused layer-pairs
constexpr int OUT_DIM  = 8;
constexpr float INV_TAU = 0.1f;

// Tiling. LESSON (R3): LDS gather instrs per block are independent of TB, so
// cost/batch-row ~ 1/TB; TB=8 (144KB LDS) is max. TB=4 @ 2 blocks/CU
// regressed 2x (both blocks share ONE LDS pipe/CU).
// LESSON (R4/R6/R7): at NTH=1024 the backend allocates 64 VGPR and SPILLS
// past it (WRITE_SIZE 128KB -> 47-104MB); __launch_bounds__(NTH,4) did NOT
// raise the cap (R7 A/B: identical binary). Keep per-thread live state at
// R5's level: no cross-tile prefetch arrays, no wide coef prefetch.
// This round: persistent 2-tile blocks via a RUNTIME (#pragma unroll 1)
// loop with the R5 body unchanged -> register profile == R5.
constexpr int TB     = 8;           // batch rows per tile (8 fp16 = uint4)
constexpr int NTILES = 2;           // batch tiles per block (persistent)
constexpr int NTH    = 1024;        // threads per block (16 waves)
constexpr int NPT    = HIDDEN / NTH;// neurons per thread = 8 (strided by 1024)
constexpr int NWAVES = NTH / 64;    // 16

__device__ __forceinline__ __half2 u2h(unsigned int u) {
    union { unsigned int u; __half2 h; } v; v.u = u; return v.h;
}
__device__ __forceinline__ unsigned int h2u(__half2 h) {
    union { unsigned int u; __half2 h; } v; v.h = h; return v.u;
}

// pack 4 fp32 -> 4 fp16 in a uint2
__device__ __forceinline__ uint2 pack4(float4 v) {
    __half2 lo = __float22half2_rn(make_float2(v.x, v.y));
    __half2 hi = __float22half2_rn(make_float2(v.z, v.w));
    uint2 r; r.x = h2u(lo); r.y = h2u(hi); return r;
}

// ---------------------------------------------------------------------------
// Prep pass 1: per-layer gate coefs (coalesced, one softmax per (l,j)).
//   coefs[l*H+j] = 4 fp16 (c0,c1 | c2,c3)
// ---------------------------------------------------------------------------
__global__ void prep_coef(const float* __restrict__ logic_w,
                          uint2* __restrict__ coefs, int n)
{
    int id = blockIdx.x * blockDim.x + threadIdx.x;
    if (id >= n) return;

    const float4* w4 = (const float4*)(logic_w + (size_t)id * 16);
    float4 wa = w4[0], wb = w4[1], wc = w4[2], wd = w4[3];
    float wv[16] = {wa.x, wa.y, wa.z, wa.w, wb.x, wb.y, wb.z, wb.w,
                    wc.x, wc.y, wc.z, wc.w, wd.x, wd.y, wd.z, wd.w};
    float m = wv[0];
#pragma unroll
    for (int i = 1; i < 16; ++i) m = fmaxf(m, wv[i]);
    float e[16];
    float s = 0.f;
#pragma unroll
    for (int i = 0; i < 16; ++i) { e[i] = expf(wv[i] - m); s += e[i]; }
    float inv = 1.f / s;
    const float G0[16] = {0,0,0,0,0,0,0,0, 1,1,1,1,1,1,1,1};
    const float G1[16] = {0,0,1,1,0,0,1,1, -1,-1,0,0,-1,-1,0,0};
    const float G2[16] = {0,0,0,0,1,1,1,1, -1,-1,-1,-1,0,0,0,0};
    const float G3[16] = {0,1,-1,0,-1,0,-2,-1, 1,2,0,1,0,1,-1,0};
    float c0 = 0.f, c1 = 0.f, c2 = 0.f, c3 = 0.f;
#pragma unroll
    for (int i = 0; i < 16; ++i) {
        float pv = e[i] * inv;
        c0 = fmaf(pv, G0[i], c0);
        c1 = fmaf(pv, G1[i], c1);
        c2 = fmaf(pv, G2[i], c2);
        c3 = fmaf(pv, G3[i], c3);
    }
    coefs[id] = pack4(make_float4(c0, c1, c2, c3));
}

// ---------------------------------------------------------------------------
// Prep pass 2: fused per-stage records (pure gather/pack; coef table is
// L2-resident 384 KB). Stage s = layers (2s, 2s+1); output neuron j with
// parents pa,pb:
//   idx4p[s*H+j] = {gaa|gba<<16, gab|gbb<<16}  (grandparent input indices)
//   cABp [s*H+j] = coefs[lbot,pa], coefs[lbot,pb]
//   cCp  [s*H+j] = coefs[ltop,j]
// Gate math in net_kernel is the identical fp16 sequence as unfused, so
// stage-boundary h values are bitwise-identical to the layer-by-layer code.
// ---------------------------------------------------------------------------
__global__ void prep_fuse(const uint2* __restrict__ coefs,
                          const int* __restrict__ idx0_a,
                          const int* __restrict__ idx0_b,
                          const int* __restrict__ idx_a,
                          const int* __restrict__ idx_b,
                          uint4* __restrict__ cABp,
                          uint2* __restrict__ idx4p,
                          uint2* __restrict__ cCp, int n)
{
    int id = blockIdx.x * blockDim.x + threadIdx.x;
    if (id >= n) return;
    const int s = id >> 13;            // / HIDDEN
    const int j = id & (HIDDEN - 1);
    const int ltop = 2 * s + 1;
    const int lbot = 2 * s;

    const int pa = idx_a[(size_t)(ltop - 1) * HIDDEN + j];
    const int pb = idx_b[(size_t)(ltop - 1) * HIDDEN + j];

    int gaa, gba, gab, gbb;
    if (s == 0) {      // bottom layer indexes into IN_DIM inputs
        gaa = idx0_a[pa]; gba = idx0_b[pa];
        gab = idx0_a[pb]; gbb = idx0_b[pb];
    } else {
        const int* A  = idx_a + (size_t)(lbot - 1) * HIDDEN;
        const int* Bv = idx_b + (size_t)(lbot - 1) * HIDDEN;
        gaa = A[pa]; gba = Bv[pa];
        gab = A[pb]; gbb = Bv[pb];
    }
    idx4p[id] = make_uint2((unsigned)gaa | ((unsigned)gba << 16),
                           (unsigned)gab | ((unsigned)gbb << 16));

    uint2 cA = coefs[(size_t)lbot * HIDDEN + pa];
    uint2 cB = coefs[(size_t)lbot * HIDDEN + pb];
    cABp[id] = make_uint4(cA.x, cA.y, cB.x, cB.y);
    cCp[id]  = coefs[(size_t)ltop * HIDDEN + j];
}

// gate in packed fp16 over 8 batch rows (uint4 = 4x half2):
// r = (c0 + c1*a) + b*(c2 + c3*a)
__device__ __forceinline__ uint4 gate8(uint4 a, uint4 b, uint2 c) {
    __half2 cp01 = u2h(c.x), cp23 = u2h(c.y);
    __half2 c0 = __low2half2(cp01), c1 = __high2half2(cp01);
    __half2 c2 = __low2half2(cp23), c3 = __high2half2(cp23);
    uint4 r;
    {
        __half2 av = u2h(a.x), bv = u2h(b.x);
        r.x = h2u(__hfma2(bv, __hfma2(c3, av, c2), __hfma2(c1, av, c0)));
    }
    {
        __half2 av = u2h(a.y), bv = u2h(b.y);
        r.y = h2u(__hfma2(bv, __hfma2(c3, av, c2), __hfma2(c1, av, c0)));
    }
    {
        __half2 av = u2h(a.z), bv = u2h(b.z);
        r.z = h2u(__hfma2(bv, __hfma2(c3, av, c2), __hfma2(c1, av, c0)));
    }
    {
        __half2 av = u2h(a.w), bv = u2h(b.w);
        r.w = h2u(__hfma2(bv, __hfma2(c3, av, c2), __hfma2(c1, av, c0)));
    }
    return r;
}

// ---------------------------------------------------------------------------
// Kernel 2: fused network (3 stages x 2 layers), TB=8 rows/tile, persistent
// blocks processing NTILES=2 tiles via a RUNTIME loop (unroll 1) whose body
// is exactly the proven R5 kernel: serial x-load at loop top, no cross-tile
// register state. Saves the 2nd block-launch round per CU; register profile
// matches R5 (52 VGPR, no spills).
// Hazards: epilogue barriers order all h/hx reads of tile t before tile
// t+1's hx/h writes (warr + vals barriers are unconditional).
// ---------------------------------------------------------------------------
__global__ __launch_bounds__(NTH) void net_kernel(
    const float*  __restrict__ x,
    const uint4*  __restrict__ cABp,
    const uint2*  __restrict__ idx4p,
    const uint2*  __restrict__ cCp,
    const float*  __restrict__ scaler_w, const float* __restrict__ scaler_b,
    float* __restrict__ out)
{
    __shared__ uint4 h[HIDDEN];             // 128 KB: 8 fp16 rows / neuron
    __shared__ uint4 hx[IN_DIM];            // 16 KB
    __shared__ float warr[NWAVES][TB];      // 512 B
    __shared__ float vals[TB][OUT_DIM];     // 256 B

    const int tid = threadIdx.x;
    const int b0  = blockIdx.x * (TB * NTILES);

    uint2 ij[NPT], ijn[NPT];     // 4 packed 16-bit gather indices per record
    uint4 acc[NPT];

#pragma unroll 1
    for (int t = 0; t < NTILES; ++t) {
        const int bt = b0 + t * TB;

        // Input tile: load + binarize (NTH == IN_DIM: one column per thread)
        {
            float v[TB];
#pragma unroll
            for (int r = 0; r < TB; ++r)
                v[r] = (x[(size_t)(bt + r) * IN_DIM + tid] > 0.5f) ? 1.f : 0.f;
            uint4 p;
            p.x = h2u(__floats2half2_rn(v[0], v[1]));
            p.y = h2u(__floats2half2_rn(v[2], v[3]));
            p.z = h2u(__floats2half2_rn(v[4], v[5]));
            p.w = h2u(__floats2half2_rn(v[6], v[7]));
            hx[tid] = p;
        }

        // Stage-0 index table (overlaps x loads / hx writes)
#pragma unroll
        for (int k = 0; k < NPT; ++k) ij[k] = idx4p[k * NTH + tid];

        __syncthreads();         // hx visible

        // Stage 0: gather from hx, write h (disjoint -> no barrier between)
#pragma unroll
        for (int k = 0; k < NPT; ++k) ijn[k] = idx4p[HIDDEN + k * NTH + tid];
#pragma unroll
        for (int k = 0; k < NPT; ++k) {
            uint2 p = ij[k];
            uint4 x1 = hx[p.x & 0xffffu], x2 = hx[p.x >> 16];
            uint4 x3 = hx[p.y & 0xffffu], x4 = hx[p.y >> 16];
            uint4 cab = cABp[k * NTH + tid];
            uint2 cc  = cCp[k * NTH + tid];
            uint4 u = gate8(x1, x2, make_uint2(cab.x, cab.y));
            uint4 v = gate8(x3, x4, make_uint2(cab.z, cab.w));
            acc[k] = gate8(u, v, cc);
        }
#pragma unroll
        for (int k = 0; k < NPT; ++k) h[k * NTH + tid] = acc[k];
        __syncthreads();

        // Stages 1..2: in-place on h (all reads land in regs before writes)
#pragma unroll
        for (int s = 1; s < N_STAGES; ++s) {
#pragma unroll
            for (int k = 0; k < NPT; ++k) ij[k] = ijn[k];
            if (s < N_STAGES - 1) {
#pragma unroll
                for (int k = 0; k < NPT; ++k)
                    ijn[k] = idx4p[(size_t)(s + 1) * HIDDEN + k * NTH + tid];
            }
#pragma unroll
            for (int k = 0; k < NPT; ++k) {
                uint2 p = ij[k];
                uint4 x1 = h[p.x & 0xffffu], x2 = h[p.x >> 16];
                uint4 x3 = h[p.y & 0xffffu], x4 = h[p.y >> 16];
                uint4 cab = cABp[(size_t)s * HIDDEN + k * NTH + tid];
                uint2 cc  = cCp[(size_t)s * HIDDEN + k * NTH + tid];
                uint4 u = gate8(x1, x2, make_uint2(cab.x, cab.y));
                uint4 v = gate8(x3, x4, make_uint2(cab.z, cab.w));
                acc[k] = gate8(u, v, cc);
            }
            __syncthreads();    // all reads of h done
#pragma unroll
            for (int k = 0; k < NPT; ++k) h[k * NTH + tid] = acc[k];
            __syncthreads();
        }

        // Epilogue: group k = tid>>7; sum 8 neurons at stride 128 (uniform
        // banks), fp32 accumulation; 64-lane butterfly; cross-wave combine.
        {
            const int k    = tid >> 7;
            const int base = k * 1024 + (tid & 127);
            float s[TB] = {0.f, 0.f, 0.f, 0.f, 0.f, 0.f, 0.f, 0.f};
#pragma unroll
            for (int i = 0; i < 8; ++i) {
                uint4 tt = h[base + 128 * i];
                float2 f0 = __half22float2(u2h(tt.x));
                float2 f1 = __half22float2(u2h(tt.y));
                float2 f2 = __half22float2(u2h(tt.z));
                float2 f3 = __half22float2(u2h(tt.w));
                s[0] += f0.x; s[1] += f0.y; s[2] += f1.x; s[3] += f1.y;
                s[4] += f2.x; s[5] += f2.y; s[6] += f3.x; s[7] += f3.y;
            }
#pragma unroll
            for (int off = 32; off > 0; off >>= 1) {
#pragma unroll
                for (int r = 0; r < TB; ++r) s[r] += __shfl_down(s[r], off);
            }
            if ((tid & 63) == 0) {
#pragma unroll
                for (int r = 0; r < TB; ++r) warr[tid >> 6][r] = s[r];
            }
        }
        __syncthreads();   // orders h/hx reads before next tile's writes
        if (tid < TB * OUT_DIM) {   // 64 threads: values, then scaler GEMV
            int r = tid >> 3;
            int k = tid & 7;
            vals[r][k] = (warr[2 * k][r] + warr[2 * k + 1][r]) * INV_TAU;
        }
        __syncthreads();
        if (tid < TB * OUT_DIM) {
            int r = tid >> 3;
            int o = tid & 7;
            float q = scaler_b[o];
#pragma unroll
            for (int k = 0; k < OUT_DIM; ++k)
                q = fmaf(vals[r][k], scaler_w[o * OUT_DIM + k], q);
            out[(size_t)(bt + r) * OUT_DIM + o] = q;
        }
    }
}

extern "C" void kernel_launch(void* const* d_in, const int* in_sizes, int n_in,
                              void* d_out, int out_size, void* d_ws, size_t ws_size,
                              hipStream_t stream)
{
    const float* x        = (const float*)d_in[0];
    const float* logic_w  = (const float*)d_in[1];
    const float* scaler_w = (const float*)d_in[2];
    const float* scaler_b = (const float*)d_in[3];
    const int*   idx0_a   = (const int*)d_in[4];
    const int*   idx0_b   = (const int*)d_in[5];
    const int*   idx_a    = (const int*)d_in[6];
    const int*   idx_b    = (const int*)d_in[7];
    float* out = (float*)d_out;

    const int nc = N_LAYERS * HIDDEN;                // 49152 per-layer coefs
    const int nf = N_STAGES * HIDDEN;                // 24576 fused records
    char* ws = (char*)d_ws;
    uint2* coefs = (uint2*)ws;                                   ws += (size_t)nc * sizeof(uint2); // 384 KB
    uint4* cABp  = (uint4*)ws;                                   ws += (size_t)nf * sizeof(uint4); // 384 KB
    uint2* idx4p = (uint2*)ws;                                   ws += (size_t)nf * sizeof(uint2); // 192 KB
    uint2* cCp   = (uint2*)ws;                                   // 192 KB

    prep_coef<<<(nc + 255) / 256, 256, 0, stream>>>(logic_w, coefs, nc);
    prep_fuse<<<(nf + 255) / 256, 256, 0, stream>>>(coefs, idx0_a, idx0_b,
                                                    idx_a, idx_b, cABp, idx4p, cCp, nf);
    net_kernel<<<BATCH / (TB * NTILES), NTH, 0, stream>>>(x, cABp, idx4p, cCp,
                                                          scaler_w, scaler_b, out);
}

// Round 9
// 116.199 us; speedup vs baseline: 2.8213x; 2.8213x over previous
//
#include <hip/hip_runtime.h>
#include <hip/hip_fp16.h>

// Problem constants (from reference)
constexpr int BATCH    = 4096;
constexpr int IN_DIM   = 1024;
constexpr int HIDDEN   = 8192;
constexpr int N_LAYERS = 6;
constexpr int N_STAGES = N_LAYERS / 2;   // 3 fused layer-pairs
constexpr int OUT_DIM  = 8;
constexpr float INV_TAU = 0.1f;

// Tiling. LESSON (R3): LDS gather instrs per block are independent of TB, so
// cost/batch-row ~ 1/TB; TB=8 (144KB LDS) is max. TB=4 @ 2 blocks/CU
// regressed 2x (both blocks share ONE LDS pipe/CU).
// LESSON (R4/R6/R7/R8): at NTH=1024 the backend allocates 64 VGPR, spills
// past it (WRITE_SIZE 128KB -> 47/104/338MB), and __launch_bounds__(NTH,4)
// does NOT raise the cap. ANY enclosing tile-loop (unrolled or runtime)
// around this body triggers the spill. Keep exactly this single-tile
// structure: 52 VGPR, no scratch.
constexpr int TB   = 8;             // batch rows per workgroup (8 fp16 = uint4)
constexpr int NTH  = 1024;          // threads per block (16 waves)
constexpr int NPT  = HIDDEN / NTH;  // neurons per thread = 8 (strided by 1024)
constexpr int NWAVES = NTH / 64;    // 16

__device__ __forceinline__ __half2 u2h(unsigned int u) {
    union { unsigned int u; __half2 h; } v; v.u = u; return v.h;
}
__device__ __forceinline__ unsigned int h2u(__half2 h) {
    union { unsigned int u; __half2 h; } v; v.h = h; return v.u;
}

// pack 4 fp32 -> 4 fp16 in a uint2
__device__ __forceinline__ uint2 pack4(float4 v) {
    __half2 lo = __float22half2_rn(make_float2(v.x, v.y));
    __half2 hi = __float22half2_rn(make_float2(v.z, v.w));
    uint2 r; r.x = h2u(lo); r.y = h2u(hi); return r;
}

// ---------------------------------------------------------------------------
// Prep pass 1: per-layer gate coefs (coalesced, one softmax per (l,j)).
//   coefs[l*H+j] = 4 fp16 (c0,c1 | c2,c3)
// ---------------------------------------------------------------------------
__global__ void prep_coef(const float* __restrict__ logic_w,
                          uint2* __restrict__ coefs, int n)
{
    int id = blockIdx.x * blockDim.x + threadIdx.x;
    if (id >= n) return;

    const float4* w4 = (const float4*)(logic_w + (size_t)id * 16);
    float4 wa = w4[0], wb = w4[1], wc = w4[2], wd = w4[3];
    float wv[16] = {wa.x, wa.y, wa.z, wa.w, wb.x, wb.y, wb.z, wb.w,
                    wc.x, wc.y, wc.z, wc.w, wd.x, wd.y, wd.z, wd.w};
    float m = wv[0];
#pragma unroll
    for (int i = 1; i < 16; ++i) m = fmaxf(m, wv[i]);
    float e[16];
    float s = 0.f;
#pragma unroll
    for (int i = 0; i < 16; ++i) { e[i] = expf(wv[i] - m); s += e[i]; }
    float inv = 1.f / s;
    const float G0[16] = {0,0,0,0,0,0,0,0, 1,1,1,1,1,1,1,1};
    const float G1[16] = {0,0,1,1,0,0,1,1, -1,-1,0,0,-1,-1,0,0};
    const float G2[16] = {0,0,0,0,1,1,1,1, -1,-1,-1,-1,0,0,0,0};
    const float G3[16] = {0,1,-1,0,-1,0,-2,-1, 1,2,0,1,0,1,-1,0};
    float c0 = 0.f, c1 = 0.f, c2 = 0.f, c3 = 0.f;
#pragma unroll
    for (int i = 0; i < 16; ++i) {
        float pv = e[i] * inv;
        c0 = fmaf(pv, G0[i], c0);
        c1 = fmaf(pv, G1[i], c1);
        c2 = fmaf(pv, G2[i], c2);
        c3 = fmaf(pv, G3[i], c3);
    }
    coefs[id] = pack4(make_float4(c0, c1, c2, c3));
}

// ---------------------------------------------------------------------------
// Prep pass 2: fused per-stage records (pure gather/pack; coef table is
// L2-resident 384 KB). Stage s = layers (2s, 2s+1); output neuron j with
// parents pa,pb:
//   idx4p[s*H+j] = {gaa|gba<<16, gab|gbb<<16}  (grandparent input indices)
//   cABp [s*H+j] = coefs[lbot,pa], coefs[lbot,pb]
//   cCp  [s*H+j] = coefs[ltop,j]
// Gate math in net_kernel is the identical fp16 sequence as unfused, so
// stage-boundary h values are bitwise-identical to the layer-by-layer code.
// ---------------------------------------------------------------------------
__global__ void prep_fuse(const uint2* __restrict__ coefs,
                          const int* __restrict__ idx0_a,
                          const int* __restrict__ idx0_b,
                          const int* __restrict__ idx_a,
                          const int* __restrict__ idx_b,
                          uint4* __restrict__ cABp,
                          uint2* __restrict__ idx4p,
                          uint2* __restrict__ cCp, int n)
{
    int id = blockIdx.x * blockDim.x + threadIdx.x;
    if (id >= n) return;
    const int s = id >> 13;            // / HIDDEN
    const int j = id & (HIDDEN - 1);
    const int ltop = 2 * s + 1;
    const int lbot = 2 * s;

    const int pa = idx_a[(size_t)(ltop - 1) * HIDDEN + j];
    const int pb = idx_b[(size_t)(ltop - 1) * HIDDEN + j];

    int gaa, gba, gab, gbb;
    if (s == 0) {      // bottom layer indexes into IN_DIM inputs
        gaa = idx0_a[pa]; gba = idx0_b[pa];
        gab = idx0_a[pb]; gbb = idx0_b[pb];
    } else {
        const int* A  = idx_a + (size_t)(lbot - 1) * HIDDEN;
        const int* Bv = idx_b + (size_t)(lbot - 1) * HIDDEN;
        gaa = A[pa]; gba = Bv[pa];
        gab = A[pb]; gbb = Bv[pb];
    }
    idx4p[id] = make_uint2((unsigned)gaa | ((unsigned)gba << 16),
                           (unsigned)gab | ((unsigned)gbb << 16));

    uint2 cA = coefs[(size_t)lbot * HIDDEN + pa];
    uint2 cB = coefs[(size_t)lbot * HIDDEN + pb];
    cABp[id] = make_uint4(cA.x, cA.y, cB.x, cB.y);
    cCp[id]  = coefs[(size_t)ltop * HIDDEN + j];
}

// gate in packed fp16 over 8 batch rows (uint4 = 4x half2):
// r = (c0 + c1*a) + b*(c2 + c3*a)
__device__ __forceinline__ uint4 gate8(uint4 a, uint4 b, uint2 c) {
    __half2 cp01 = u2h(c.x), cp23 = u2h(c.y);
    __half2 c0 = __low2half2(cp01), c1 = __high2half2(cp01);
    __half2 c2 = __low2half2(cp23), c3 = __high2half2(cp23);
    uint4 r;
    {
        __half2 av = u2h(a.x), bv = u2h(b.x);
        r.x = h2u(__hfma2(bv, __hfma2(c3, av, c2), __hfma2(c1, av, c0)));
    }
    {
        __half2 av = u2h(a.y), bv = u2h(b.y);
        r.y = h2u(__hfma2(bv, __hfma2(c3, av, c2), __hfma2(c1, av, c0)));
    }
    {
        __half2 av = u2h(a.z), bv = u2h(b.z);
        r.z = h2u(__hfma2(bv, __hfma2(c3, av, c2), __hfma2(c1, av, c0)));
    }
    {
        __half2 av = u2h(a.w), bv = u2h(b.w);
        r.w = h2u(__hfma2(bv, __hfma2(c3, av, c2), __hfma2(c1, av, c0)));
    }
    return r;
}

// ---------------------------------------------------------------------------
// Kernel 2: fused network, 3 stages of 2 layers each, TB=8 rows/block.
// Per stage each output neuron gathers its 4 grandparent values (b128, the
// dominant LDS cost) and evaluates 3 gates in registers; LDS writes and
// barriers are HALVED vs the unfused 6-layer version. Coefs are loaded
// in-loop (no long-lived register arrays -> no spills, see R4 lesson);
// only the 2-dword next-stage indices are prefetched.
// ---------------------------------------------------------------------------
__global__ __launch_bounds__(NTH) void net_kernel(
    const float*  __restrict__ x,
    const uint4*  __restrict__ cABp,
    const uint2*  __restrict__ idx4p,
    const uint2*  __restrict__ cCp,
    const float*  __restrict__ scaler_w, const float* __restrict__ scaler_b,
    float* __restrict__ out)
{
    __shared__ uint4 h[HIDDEN];             // 128 KB: 8 fp16 rows / neuron
    __shared__ uint4 hx[IN_DIM];            // 16 KB
    __shared__ float warr[NWAVES][TB];      // 512 B
    __shared__ float vals[TB][OUT_DIM];     // 256 B

    const int tid = threadIdx.x;
    const int b0  = blockIdx.x * TB;

    // Load + binarize input tile (NTH == IN_DIM: one column per thread)
    {
        float v[TB];
#pragma unroll
        for (int r = 0; r < TB; ++r)
            v[r] = (x[(size_t)(b0 + r) * IN_DIM + tid] > 0.5f) ? 1.f : 0.f;
        uint4 p;
        p.x = h2u(__floats2half2_rn(v[0], v[1]));
        p.y = h2u(__floats2half2_rn(v[2], v[3]));
        p.z = h2u(__floats2half2_rn(v[4], v[5]));
        p.w = h2u(__floats2half2_rn(v[6], v[7]));
        hx[tid] = p;
    }

    uint2 ij[NPT], ijn[NPT];     // 4 packed 16-bit gather indices per record
    uint4 acc[NPT];

    // Stage-0 index table up-front (overlaps x loads / hx writes)
#pragma unroll
    for (int k = 0; k < NPT; ++k) ij[k] = idx4p[k * NTH + tid];

    __syncthreads();             // hx visible

    // Stage 0: gather from hx, write h (disjoint arrays -> no barrier between)
#pragma unroll
    for (int k = 0; k < NPT; ++k) ijn[k] = idx4p[HIDDEN + k * NTH + tid];
#pragma unroll
    for (int k = 0; k < NPT; ++k) {
        uint2 p = ij[k];
        uint4 x1 = hx[p.x & 0xffffu], x2 = hx[p.x >> 16];
        uint4 x3 = hx[p.y & 0xffffu], x4 = hx[p.y >> 16];
        uint4 cab = cABp[k * NTH + tid];
        uint2 cc  = cCp[k * NTH + tid];
        uint4 u = gate8(x1, x2, make_uint2(cab.x, cab.y));
        uint4 v = gate8(x3, x4, make_uint2(cab.z, cab.w));
        acc[k] = gate8(u, v, cc);
    }
#pragma unroll
    for (int k = 0; k < NPT; ++k) h[k * NTH + tid] = acc[k];
    __syncthreads();

    // Stages 1..2: in-place on h (all reads land in regs before writes)
#pragma unroll
    for (int s = 1; s < N_STAGES; ++s) {
#pragma unroll
        for (int k = 0; k < NPT; ++k) ij[k] = ijn[k];
        if (s < N_STAGES - 1) {
#pragma unroll
            for (int k = 0; k < NPT; ++k)
                ijn[k] = idx4p[(size_t)(s + 1) * HIDDEN + k * NTH + tid];
        }
#pragma unroll
        for (int k = 0; k < NPT; ++k) {
            uint2 p = ij[k];
            uint4 x1 = h[p.x & 0xffffu], x2 = h[p.x >> 16];
            uint4 x3 = h[p.y & 0xffffu], x4 = h[p.y >> 16];
            uint4 cab = cABp[(size_t)s * HIDDEN + k * NTH + tid];
            uint2 cc  = cCp[(size_t)s * HIDDEN + k * NTH + tid];
            uint4 u = gate8(x1, x2, make_uint2(cab.x, cab.y));
            uint4 v = gate8(x3, x4, make_uint2(cab.z, cab.w));
            acc[k] = gate8(u, v, cc);
        }
        __syncthreads();            // all reads of h done
#pragma unroll
        for (int k = 0; k < NPT; ++k) h[k * NTH + tid] = acc[k];
        __syncthreads();
    }

    // Epilogue: group k = tid>>7; sum 8 neurons at stride 128 (uniform banks),
    // fp32 accumulation over 8 rows; 64-lane butterfly; cross-wave combine.
    {
        const int k    = tid >> 7;
        const int base = k * 1024 + (tid & 127);
        float s[TB] = {0.f, 0.f, 0.f, 0.f, 0.f, 0.f, 0.f, 0.f};
#pragma unroll
        for (int i = 0; i < 8; ++i) {
            uint4 t = h[base + 128 * i];
            float2 f0 = __half22float2(u2h(t.x));
            float2 f1 = __half22float2(u2h(t.y));
            float2 f2 = __half22float2(u2h(t.z));
            float2 f3 = __half22float2(u2h(t.w));
            s[0] += f0.x; s[1] += f0.y; s[2] += f1.x; s[3] += f1.y;
            s[4] += f2.x; s[5] += f2.y; s[6] += f3.x; s[7] += f3.y;
        }
#pragma unroll
        for (int off = 32; off > 0; off >>= 1) {
#pragma unroll
            for (int r = 0; r < TB; ++r) s[r] += __shfl_down(s[r], off);
        }
        if ((tid & 63) == 0) {
#pragma unroll
            for (int r = 0; r < TB; ++r) warr[tid >> 6][r] = s[r];
        }
    }
    __syncthreads();
    if (tid < TB * OUT_DIM) {       // 64 threads: values, then scaler GEMV
        int r = tid >> 3;
        int k = tid & 7;
        vals[r][k] = (warr[2 * k][r] + warr[2 * k + 1][r]) * INV_TAU;
    }
    __syncthreads();
    if (tid < TB * OUT_DIM) {
        int r = tid >> 3;
        int o = tid & 7;
        float q = scaler_b[o];
#pragma unroll
        for (int k = 0; k < OUT_DIM; ++k)
            q = fmaf(vals[r][k], scaler_w[o * OUT_DIM + k], q);
        out[(size_t)(b0 + r) * OUT_DIM + o] = q;
    }
}

extern "C" void kernel_launch(void* const* d_in, const int* in_sizes, int n_in,
                              void* d_out, int out_size, void* d_ws, size_t ws_size,
                              hipStream_t stream)
{
    const float* x        = (const float*)d_in[0];
    const float* logic_w  = (const float*)d_in[1];
    const float* scaler_w = (const float*)d_in[2];
    const float* scaler_b = (const float*)d_in[3];
    const int*   idx0_a   = (const int*)d_in[4];
    const int*   idx0_b   = (const int*)d_in[5];
    const int*   idx_a    = (const int*)d_in[6];
    const int*   idx_b    = (const int*)d_in[7];
    float* out = (float*)d_out;

    const int nc = N_LAYERS * HIDDEN;                // 49152 per-layer coefs
    const int nf = N_STAGES * HIDDEN;                // 24576 fused records
    char* ws = (char*)d_ws;
    uint2* coefs = (uint2*)ws;                                   ws += (size_t)nc * sizeof(uint2); // 384 KB
    uint4* cABp  = (uint4*)ws;                                   ws += (size_t)nf * sizeof(uint4); // 384 KB
    uint2* idx4p = (uint2*)ws;                                   ws += (size_t)nf * sizeof(uint2); // 192 KB
    uint2* cCp   = (uint2*)ws;                                   // 192 KB

    prep_coef<<<(nc + 255) / 256, 256, 0, stream>>>(logic_w, coefs, nc);
    prep_fuse<<<(nf + 255) / 256, 256, 0, stream>>>(coefs, idx0_a, idx0_b,
                                                    idx_a, idx_b, cABp, idx4p, cCp, nf);
    net_kernel<<<BATCH / TB, NTH, 0, stream>>>(x, cABp, idx4p, cCp,
                                               scaler_w, scaler_b, out);
}

// Round 10
// 114.054 us; speedup vs baseline: 2.8744x; 1.0188x over previous
//
#include <hip/hip_runtime.h>
#include <hip/hip_fp16.h>

// Problem constants (from reference)
constexpr int BATCH    = 4096;
constexpr int IN_DIM   = 1024;
constexpr int HIDDEN   = 8192;
constexpr int N_LAYERS = 6;
constexpr int N_STAGES = N_LAYERS / 2;   // 3 fused layer-pairs
constexpr int OUT_DIM  = 8;
constexpr float INV_TAU = 0.1f;

// Tiling. LESSON (R3): LDS gather instrs per block are independent of TB, so
// cost/batch-row ~ 1/TB; TB=8 (144KB LDS) is max. TB=4 @ 2 blocks/CU
// regressed 2x (both blocks share ONE LDS pipe/CU).
// LESSON (R4/R6/R7/R8): at NTH=1024 the backend allocates 64 VGPR, spills
// past it (WRITE_SIZE 128KB -> 47/104/338MB), and __launch_bounds__(NTH,4)
// does NOT raise the cap. ANY enclosing tile-loop around this body spills.
// Keep the single-tile structure and per-thread live state minimal.
// R10: stage 2 outputs stay in registers (work distribution = epilogue
// mapping) -> deletes 128KB h write + 128KB epilogue re-read + 2 barriers.
constexpr int TB   = 8;             // batch rows per workgroup (8 fp16 = uint4)
constexpr int NTH  = 1024;          // threads per block (16 waves)
constexpr int NPT  = HIDDEN / NTH;  // neurons per thread = 8
constexpr int NWAVES = NTH / 64;    // 16

__device__ __forceinline__ __half2 u2h(unsigned int u) {
    union { unsigned int u; __half2 h; } v; v.u = u; return v.h;
}
__device__ __forceinline__ unsigned int h2u(__half2 h) {
    union { unsigned int u; __half2 h; } v; v.h = h; return v.u;
}

// pack 4 fp32 -> 4 fp16 in a uint2
__device__ __forceinline__ uint2 pack4(float4 v) {
    __half2 lo = __float22half2_rn(make_float2(v.x, v.y));
    __half2 hi = __float22half2_rn(make_float2(v.z, v.w));
    uint2 r; r.x = h2u(lo); r.y = h2u(hi); return r;
}

// ---------------------------------------------------------------------------
// Prep pass 1: per-layer gate coefs (coalesced, one softmax per (l,j)).
//   coefs[l*H+j] = 4 fp16 (c0,c1 | c2,c3)
// ---------------------------------------------------------------------------
__global__ void prep_coef(const float* __restrict__ logic_w,
                          uint2* __restrict__ coefs, int n)
{
    int id = blockIdx.x * blockDim.x + threadIdx.x;
    if (id >= n) return;

    const float4* w4 = (const float4*)(logic_w + (size_t)id * 16);
    float4 wa = w4[0], wb = w4[1], wc = w4[2], wd = w4[3];
    float wv[16] = {wa.x, wa.y, wa.z, wa.w, wb.x, wb.y, wb.z, wb.w,
                    wc.x, wc.y, wc.z, wc.w, wd.x, wd.y, wd.z, wd.w};
    float m = wv[0];
#pragma unroll
    for (int i = 1; i < 16; ++i) m = fmaxf(m, wv[i]);
    float e[16];
    float s = 0.f;
#pragma unroll
    for (int i = 0; i < 16; ++i) { e[i] = expf(wv[i] - m); s += e[i]; }
    float inv = 1.f / s;
    const float G0[16] = {0,0,0,0,0,0,0,0, 1,1,1,1,1,1,1,1};
    const float G1[16] = {0,0,1,1,0,0,1,1, -1,-1,0,0,-1,-1,0,0};
    const float G2[16] = {0,0,0,0,1,1,1,1, -1,-1,-1,-1,0,0,0,0};
    const float G3[16] = {0,1,-1,0,-1,0,-2,-1, 1,2,0,1,0,1,-1,0};
    float c0 = 0.f, c1 = 0.f, c2 = 0.f, c3 = 0.f;
#pragma unroll
    for (int i = 0; i < 16; ++i) {
        float pv = e[i] * inv;
        c0 = fmaf(pv, G0[i], c0);
        c1 = fmaf(pv, G1[i], c1);
        c2 = fmaf(pv, G2[i], c2);
        c3 = fmaf(pv, G3[i], c3);
    }
    coefs[id] = pack4(make_float4(c0, c1, c2, c3));
}

// ---------------------------------------------------------------------------
// Prep pass 2: fused per-stage records (pure gather/pack; coef table is
// L2-resident 384 KB). Stage s = layers (2s, 2s+1); output neuron j with
// parents pa,pb:
//   idx4p[s*H+j] = {gaa|gba<<16, gab|gbb<<16}  (grandparent input indices)
//   cABp [s*H+j] = coefs[lbot,pa], coefs[lbot,pb]
//   cCp  [s*H+j] = coefs[ltop,j]
// Gate math in net_kernel is the identical fp16 sequence as unfused, so
// stage-boundary h values are bitwise-identical to the layer-by-layer code.
// ---------------------------------------------------------------------------
__global__ void prep_fuse(const uint2* __restrict__ coefs,
                          const int* __restrict__ idx0_a,
                          const int* __restrict__ idx0_b,
                          const int* __restrict__ idx_a,
                          const int* __restrict__ idx_b,
                          uint4* __restrict__ cABp,
                          uint2* __restrict__ idx4p,
                          uint2* __restrict__ cCp, int n)
{
    int id = blockIdx.x * blockDim.x + threadIdx.x;
    if (id >= n) return;
    const int s = id >> 13;            // / HIDDEN
    const int j = id & (HIDDEN - 1);
    const int ltop = 2 * s + 1;
    const int lbot = 2 * s;

    const int pa = idx_a[(size_t)(ltop - 1) * HIDDEN + j];
    const int pb = idx_b[(size_t)(ltop - 1) * HIDDEN + j];

    int gaa, gba, gab, gbb;
    if (s == 0) {      // bottom layer indexes into IN_DIM inputs
        gaa = idx0_a[pa]; gba = idx0_b[pa];
        gab = idx0_a[pb]; gbb = idx0_b[pb];
    } else {
        const int* A  = idx_a + (size_t)(lbot - 1) * HIDDEN;
        const int* Bv = idx_b + (size_t)(lbot - 1) * HIDDEN;
        gaa = A[pa]; gba = Bv[pa];
        gab = A[pb]; gbb = Bv[pb];
    }
    idx4p[id] = make_uint2((unsigned)gaa | ((unsigned)gba << 16),
                           (unsigned)gab | ((unsigned)gbb << 16));

    uint2 cA = coefs[(size_t)lbot * HIDDEN + pa];
    uint2 cB = coefs[(size_t)lbot * HIDDEN + pb];
    cABp[id] = make_uint4(cA.x, cA.y, cB.x, cB.y);
    cCp[id]  = coefs[(size_t)ltop * HIDDEN + j];
}

// gate in packed fp16 over 8 batch rows (uint4 = 4x half2):
// r = (c0 + c1*a) + b*(c2 + c3*a)
__device__ __forceinline__ uint4 gate8(uint4 a, uint4 b, uint2 c) {
    __half2 cp01 = u2h(c.x), cp23 = u2h(c.y);
    __half2 c0 = __low2half2(cp01), c1 = __high2half2(cp01);
    __half2 c2 = __low2half2(cp23), c3 = __high2half2(cp23);
    uint4 r;
    {
        __half2 av = u2h(a.x), bv = u2h(b.x);
        r.x = h2u(__hfma2(bv, __hfma2(c3, av, c2), __hfma2(c1, av, c0)));
    }
    {
        __half2 av = u2h(a.y), bv = u2h(b.y);
        r.y = h2u(__hfma2(bv, __hfma2(c3, av, c2), __hfma2(c1, av, c0)));
    }
    {
        __half2 av = u2h(a.z), bv = u2h(b.z);
        r.z = h2u(__hfma2(bv, __hfma2(c3, av, c2), __hfma2(c1, av, c0)));
    }
    {
        __half2 av = u2h(a.w), bv = u2h(b.w);
        r.w = h2u(__hfma2(bv, __hfma2(c3, av, c2), __hfma2(c1, av, c0)));
    }
    return r;
}

// ---------------------------------------------------------------------------
// Kernel 2: fused network, 3 stages of 2 layers each, TB=8 rows/block.
// Stages 0-1 as before (random b128 gathers + register gates + h write).
// Stage 2: each thread computes the 8 neurons the epilogue butterfly needs
// (record ids grp*1024 + lane + 128k, grp=tid>>7, lane=tid&127; wave loads
// stay coalesced) and accumulates them into f32 registers directly — no
// final h write, no epilogue LDS re-read, 2 fewer barriers.
// ---------------------------------------------------------------------------
__global__ __launch_bounds__(NTH) void net_kernel(
    const float*  __restrict__ x,
    const uint4*  __restrict__ cABp,
    const uint2*  __restrict__ idx4p,
    const uint2*  __restrict__ cCp,
    const float*  __restrict__ scaler_w, const float* __restrict__ scaler_b,
    float* __restrict__ out)
{
    __shared__ uint4 h[HIDDEN];             // 128 KB: 8 fp16 rows / neuron
    __shared__ uint4 hx[IN_DIM];            // 16 KB
    __shared__ float warr[NWAVES][TB];      // 512 B
    __shared__ float vals[TB][OUT_DIM];     // 256 B

    const int tid = threadIdx.x;
    const int b0  = blockIdx.x * TB;

    // Load + binarize input tile (NTH == IN_DIM: one column per thread)
    {
        float v[TB];
#pragma unroll
        for (int r = 0; r < TB; ++r)
            v[r] = (x[(size_t)(b0 + r) * IN_DIM + tid] > 0.5f) ? 1.f : 0.f;
        uint4 p;
        p.x = h2u(__floats2half2_rn(v[0], v[1]));
        p.y = h2u(__floats2half2_rn(v[2], v[3]));
        p.z = h2u(__floats2half2_rn(v[4], v[5]));
        p.w = h2u(__floats2half2_rn(v[6], v[7]));
        hx[tid] = p;
    }

    uint2 ij[NPT], ijn[NPT];     // 4 packed 16-bit gather indices per record
    uint4 acc[NPT];

    // Stage-0 index table up-front (overlaps x loads / hx writes)
#pragma unroll
    for (int k = 0; k < NPT; ++k) ij[k] = idx4p[k * NTH + tid];

    __syncthreads();             // hx visible

    // Stage 0: gather from hx, write h (disjoint arrays -> no barrier between)
#pragma unroll
    for (int k = 0; k < NPT; ++k) ijn[k] = idx4p[HIDDEN + k * NTH + tid];
#pragma unroll
    for (int k = 0; k < NPT; ++k) {
        uint2 p = ij[k];
        uint4 x1 = hx[p.x & 0xffffu], x2 = hx[p.x >> 16];
        uint4 x3 = hx[p.y & 0xffffu], x4 = hx[p.y >> 16];
        uint4 cab = cABp[k * NTH + tid];
        uint2 cc  = cCp[k * NTH + tid];
        uint4 u = gate8(x1, x2, make_uint2(cab.x, cab.y));
        uint4 v = gate8(x3, x4, make_uint2(cab.z, cab.w));
        acc[k] = gate8(u, v, cc);
    }
#pragma unroll
    for (int k = 0; k < NPT; ++k) h[k * NTH + tid] = acc[k];
    __syncthreads();

    // Stage-2 work distribution = epilogue mapping: record ids
    // pbase + 128*k with pbase = grp*1024 + lane (coalesced per wave).
    const int grp   = tid >> 7;
    const int lane  = tid & 127;
    const int pbase = grp * 1024 + lane;

    // Stage 1: in-place on h; prefetch stage-2 PERMUTED indices
    {
#pragma unroll
        for (int k = 0; k < NPT; ++k) ij[k] = ijn[k];
#pragma unroll
        for (int k = 0; k < NPT; ++k)
            ijn[k] = idx4p[2 * HIDDEN + pbase + 128 * k];
#pragma unroll
        for (int k = 0; k < NPT; ++k) {
            uint2 p = ij[k];
            uint4 x1 = h[p.x & 0xffffu], x2 = h[p.x >> 16];
            uint4 x3 = h[p.y & 0xffffu], x4 = h[p.y >> 16];
            uint4 cab = cABp[(size_t)HIDDEN + k * NTH + tid];
            uint2 cc  = cCp[(size_t)HIDDEN + k * NTH + tid];
            uint4 u = gate8(x1, x2, make_uint2(cab.x, cab.y));
            uint4 v = gate8(x3, x4, make_uint2(cab.z, cab.w));
            acc[k] = gate8(u, v, cc);
        }
        __syncthreads();            // all reads of h done
#pragma unroll
        for (int k = 0; k < NPT; ++k) h[k * NTH + tid] = acc[k];
        __syncthreads();
    }

    // Stage 2 + epilogue accumulation fused: results never touch LDS.
    float s[TB] = {0.f, 0.f, 0.f, 0.f, 0.f, 0.f, 0.f, 0.f};
#pragma unroll
    for (int k = 0; k < NPT; ++k) {
        uint2 p = ijn[k];
        uint4 x1 = h[p.x & 0xffffu], x2 = h[p.x >> 16];
        uint4 x3 = h[p.y & 0xffffu], x4 = h[p.y >> 16];
        uint4 cab = cABp[(size_t)2 * HIDDEN + pbase + 128 * k];
        uint2 cc  = cCp[(size_t)2 * HIDDEN + pbase + 128 * k];
        uint4 u = gate8(x1, x2, make_uint2(cab.x, cab.y));
        uint4 v = gate8(x3, x4, make_uint2(cab.z, cab.w));
        uint4 a = gate8(u, v, cc);
        float2 f0 = __half22float2(u2h(a.x));
        float2 f1 = __half22float2(u2h(a.y));
        float2 f2 = __half22float2(u2h(a.z));
        float2 f3 = __half22float2(u2h(a.w));
        s[0] += f0.x; s[1] += f0.y; s[2] += f1.x; s[3] += f1.y;
        s[4] += f2.x; s[5] += f2.y; s[6] += f3.x; s[7] += f3.y;
    }

    // 64-lane butterfly; cross-wave combine (unchanged from R9 epilogue).
#pragma unroll
    for (int off = 32; off > 0; off >>= 1) {
#pragma unroll
        for (int r = 0; r < TB; ++r) s[r] += __shfl_down(s[r], off);
    }
    if ((tid & 63) == 0) {
#pragma unroll
        for (int r = 0; r < TB; ++r) warr[tid >> 6][r] = s[r];
    }
    __syncthreads();
    if (tid < TB * OUT_DIM) {       // 64 threads: values, then scaler GEMV
        int r = tid >> 3;
        int k = tid & 7;
        vals[r][k] = (warr[2 * k][r] + warr[2 * k + 1][r]) * INV_TAU;
    }
    __syncthreads();
    if (tid < TB * OUT_DIM) {
        int r = tid >> 3;
        int o = tid & 7;
        float q = scaler_b[o];
#pragma unroll
        for (int k = 0; k < OUT_DIM; ++k)
            q = fmaf(vals[r][k], scaler_w[o * OUT_DIM + k], q);
        out[(size_t)(b0 + r) * OUT_DIM + o] = q;
    }
}

extern "C" void kernel_launch(void* const* d_in, const int* in_sizes, int n_in,
                              void* d_out, int out_size, void* d_ws, size_t ws_size,
                              hipStream_t stream)
{
    const float* x        = (const float*)d_in[0];
    const float* logic_w  = (const float*)d_in[1];
    const float* scaler_w = (const float*)d_in[2];
    const float* scaler_b = (const float*)d_in[3];
    const int*   idx0_a   = (const int*)d_in[4];
    const int*   idx0_b   = (const int*)d_in[5];
    const int*   idx_a    = (const int*)d_in[6];
    const int*   idx_b    = (const int*)d_in[7];
    float* out = (float*)d_out;

    const int nc = N_LAYERS * HIDDEN;                // 49152 per-layer coefs
    const int nf = N_STAGES * HIDDEN;                // 24576 fused records
    char* ws = (char*)d_ws;
    uint2* coefs = (uint2*)ws;                                   ws += (size_t)nc * sizeof(uint2); // 384 KB
    uint4* cABp  = (uint4*)ws;                                   ws += (size_t)nf * sizeof(uint4); // 384 KB
    uint2* idx4p = (uint2*)ws;                                   ws += (size_t)nf * sizeof(uint2); // 192 KB
    uint2* cCp   = (uint2*)ws;                                   // 192 KB

    prep_coef<<<(nc + 255) / 256, 256, 0, stream>>>(logic_w, coefs, nc);
    prep_fuse<<<(nf + 255) / 256, 256, 0, stream>>>(coefs, idx0_a, idx0_b,
                                                    idx_a, idx_b, cABp, idx4p, cCp, nf);
    net_kernel<<<BATCH / TB, NTH, 0, stream>>>(x, cABp, idx4p, cCp,
                                               scaler_w, scaler_b, out);
}